// Round 5
// baseline (363.613 us; speedup 1.0000x reference)
//
#include <hip/hip_runtime.h>
#include <hip/hip_bf16.h>

// Problem constants
#define HEADS   12
#define HD      64
#define NTOK    197          // N_PATCH + 1
#define BATCH   64
#define M_TOK   (BATCH*NTOK) // 12608
#define DIMC    768
#define NPAIR   (NTOK*NTOK)  // 38809
#define MPAD    224          // key/m dimension padded to 7*32

typedef __attribute__((ext_vector_type(8))) short bf16x8;  // 8 bf16 (4 VGPRs)
typedef __attribute__((ext_vector_type(4))) short s16x4;
typedef __attribute__((ext_vector_type(4))) float f32x4;

// fp32 -> bf16 round-to-nearest-even
static __device__ __forceinline__ short f2bf(float f) {
    unsigned u = __float_as_uint(f);
    unsigned r = (u + 0x7FFFu + ((u >> 16) & 1u)) >> 16;
    return (short)r;
}

// ---------------------------------------------------------------------------
// Kernel 0a: fused fp32 -> bf16 bulk convert of x, qkv_w, proj_w (one launch)
// ---------------------------------------------------------------------------
#define NX (M_TOK * DIMC)        // 9,682,944
#define NW (3 * DIMC * DIMC)     // 1,769,472
#define NP (DIMC * DIMC)         //   589,824
__global__ void cvt_kernel(const float* __restrict__ s0, short* __restrict__ d0,
                           const float* __restrict__ s1, short* __restrict__ d1,
                           const float* __restrict__ s2, short* __restrict__ d2) {
    int i = (blockIdx.x * 256 + threadIdx.x) * 4;
    const float* s; short* d;
    if (i < NX)                { s = s0 + i; d = d0 + i; }
    else if (i < NX + NW)      { s = s1 + (i - NX); d = d1 + (i - NX); }
    else if (i < NX + NW + NP) { s = s2 + (i - NX - NW); d = d2 + (i - NX - NW); }
    else return;
    const float4 v = *(const float4*)s;
    s16x4 b; b[0] = f2bf(v.x); b[1] = f2bf(v.y); b[2] = f2bf(v.z); b[3] = f2bf(v.w);
    *(s16x4*)d = b;
}

// ---------------------------------------------------------------------------
// Kernel 0b: expand rpb_table via rel_pos_index -> rpb_full[h][n*197+m]
// ---------------------------------------------------------------------------
__global__ void rpb_kernel(const float* __restrict__ table,
                           const int* __restrict__ idx,
                           float* __restrict__ rpb_full) {
    int i = blockIdx.x * 256 + threadIdx.x;
    if (i >= NPAIR) return;
    int id = idx[i];
    #pragma unroll
    for (int h = 0; h < HEADS; ++h)
        rpb_full[(size_t)h * NPAIR + i] = table[id * HEADS + h];
}

// ---------------------------------------------------------------------------
// Shared GEMM building blocks: 128x128 tile, BK=64, 4 waves of 64x64,
// 2-phase double-buffered staging.
// ---------------------------------------------------------------------------
#define STAGE(LA, LB, kt)                                                       \
    _Pragma("unroll")                                                           \
    for (int i = 0; i < 4; ++i) {                                               \
        __builtin_amdgcn_global_load_lds(                                       \
            (const __attribute__((address_space(1))) void*)(aptr[i] + (kt) * 64),\
            (__attribute__((address_space(3))) void*)&LA[(wv * 4 + i) * 512],   \
            16, 0, 0);                                                          \
        __builtin_amdgcn_global_load_lds(                                       \
            (const __attribute__((address_space(1))) void*)(bptr[i] + (kt) * 64),\
            (__attribute__((address_space(3))) void*)&LB[(wv * 4 + i) * 512],   \
            16, 0, 0);                                                          \
    }

#define COMPUTE(LA, LB)                                                         \
    _Pragma("unroll")                                                           \
    for (int ks = 0; ks < 2; ++ks) {                                            \
        bf16x8 af[4], bfr[4];                                                   \
        const int kk = ks * 32 + (g << 3);                                      \
        _Pragma("unroll")                                                       \
        for (int i = 0; i < 4; ++i)                                             \
            af[i] = *(const bf16x8*)&LA[(wr * 64 + i * 16 + c16) * 64 + kk];    \
        _Pragma("unroll")                                                       \
        for (int j = 0; j < 4; ++j)                                             \
            bfr[j] = *(const bf16x8*)&LB[(wc * 64 + j * 16 + c16) * 64 + kk];   \
        _Pragma("unroll")                                                       \
        for (int i = 0; i < 4; ++i)                                             \
            _Pragma("unroll")                                                   \
            for (int j = 0; j < 4; ++j)                                         \
                acc[i][j] = __builtin_amdgcn_mfma_f32_16x16x32_bf16(            \
                    af[i], bfr[j], acc[i][j], 0, 0, 0);                         \
    }

// ---------------------------------------------------------------------------
// Kernel 1: QKV GEMM (bf16 in), epilogue scatters q (scaled), k, v^T.
// ---------------------------------------------------------------------------
__global__ __launch_bounds__(256) void qkv_gemm_kernel(
    const short* __restrict__ xb, const short* __restrict__ wb,
    const float* __restrict__ qb, const float* __restrict__ vb,
    short* __restrict__ q_ws, short* __restrict__ k_ws,
    short* __restrict__ vt_ws) {
    __shared__ __align__(16) short lds_a0[128 * 64];
    __shared__ __align__(16) short lds_a1[128 * 64];
    __shared__ __align__(16) short lds_b0[128 * 64];
    __shared__ __align__(16) short lds_b1[128 * 64];
    const int tid  = threadIdx.x;
    const int lane = tid & 63;
    const int wv   = tid >> 6;           // 0..3
    const int wr   = wv >> 1, wc = wv & 1;
    const int bm   = blockIdx.y, bn = blockIdx.x;
    const int g    = lane >> 4, c16 = lane & 15;

    f32x4 acc[4][4] = {};

    const int lrow = lane >> 3;
    const int lcol = (lane & 7) * 8;
    const short* aptr[4];
    const short* bptr[4];
    #pragma unroll
    for (int i = 0; i < 4; ++i) {
        const int r  = (wv * 4 + i) * 8 + lrow;
        int gr = bm * 128 + r; if (gr > M_TOK - 1) gr = M_TOK - 1;
        aptr[i] = xb + (size_t)gr * DIMC + lcol;
        bptr[i] = wb + (size_t)(bn * 128 + r) * DIMC + lcol;
    }

    STAGE(lds_a0, lds_b0, 0);
    __syncthreads();
    #pragma unroll
    for (int kp = 0; kp < 6; ++kp) {
        STAGE(lds_a1, lds_b1, 2 * kp + 1);
        COMPUTE(lds_a0, lds_b0);
        __syncthreads();
        if (kp < 5) { STAGE(lds_a0, lds_b0, 2 * kp + 2); }
        COMPUTE(lds_a1, lds_b1);
        if (kp < 5) __syncthreads();
    }

    // epilogue: C/D layout col = lane&15, row = (lane>>4)*4 + reg  [m89-verified]
    #pragma unroll
    for (int i = 0; i < 4; ++i) {
        const int tbase = bm * 128 + wr * 64 + i * 16 + (g << 2);
        #pragma unroll
        for (int j = 0; j < 4; ++j) {
            const int c     = bn * 128 + wc * 64 + j * 16 + c16;
            const int which = c / DIMC;            // 0=q 1=k 2=v
            const int r     = c - which * DIMC;
            const int h     = r >> 6, d = r & 63;
            #pragma unroll
            for (int rg = 0; rg < 4; ++rg) {
                const int tt = tbase + rg;
                if (tt >= M_TOK) continue;
                const int b = tt / NTOK, n = tt - b * NTOK;
                const size_t bh = (size_t)b * HEADS + h;
                float val = acc[i][j][rg];
                if (which == 0) {
                    val = (val + qb[r]) * 0.125f;                    // q scale hd^-0.5
                    q_ws[(bh * NTOK + n) * HD + d] = f2bf(val);
                } else if (which == 1) {
                    k_ws[(bh * NTOK + n) * HD + d] = f2bf(val);
                } else {
                    val += vb[r];
                    vt_ws[(bh * HD + d) * MPAD + n] = f2bf(val);     // transposed for PV B-frags
                }
            }
        }
    }
}

// ---------------------------------------------------------------------------
// Kernel 2: attention. One block per (b,h), 4 waves; K staged once in
// XOR-swizzled LDS (shared by all waves/tiles); V read per-wave from global
// (28.7 KB -> L1-resident); P in per-wave LDS slabs. Each wave handles row
// tiles rt = wv, wv+4, wv+8 (,wv+12).
// ---------------------------------------------------------------------------
__global__ __launch_bounds__(256) void attn_kernel(
    const short* __restrict__ q_ws, const short* __restrict__ k_ws,
    const short* __restrict__ vt_ws, const float* __restrict__ rpb_full,
    short* __restrict__ o_ws) {
    __shared__ __align__(16) short k_lds[224 * 64];        // 28,672 B, swizzled
    __shared__ __align__(16) short p_lds[4 * 16 * 232];    // 29,696 B, per-wave
    const int tid  = threadIdx.x;
    const int lane = tid & 63;
    const int wv   = tid >> 6;
    const int bh   = blockIdx.x;                           // 0..767
    const int b    = bh / HEADS, h = bh - b * HEADS;
    const int g    = lane >> 4, c16 = lane & 15;
    short* p_base = p_lds + wv * (16 * 232);

    // cooperative K stage: 224 rows x 64 shorts (rows >=197 zeroed),
    // 16B chunks; swizzle col ^= (row&7)<<3 (shorts) on write AND read.
    #pragma unroll
    for (int it = 0; it < 7; ++it) {
        const int c    = tid + it * 256;    // 1792 chunks total
        const int row  = c >> 3;
        const int coff = (c & 7) * 8;
        bf16x8 v = {};
        if (row < NTOK)
            v = *(const bf16x8*)(k_ws + ((size_t)bh * NTOK + row) * HD + coff);
        *(bf16x8*)&k_lds[row * 64 + (coff ^ ((row & 7) << 3))] = v;
    }
    __syncthreads();

    for (int rt = wv; rt < 13; rt += 4) {
        // Q fragments (A-operand): row n = rt*16 + c16 (clamped), k-contig in d
        int nq = rt * 16 + c16; if (nq > NTOK - 1) nq = NTOK - 1;
        const size_t qbase = ((size_t)bh * NTOK + nq) * HD + g * 8;
        const bf16x8 qa0 = *(const bf16x8*)(q_ws + qbase);
        const bf16x8 qa1 = *(const bf16x8*)(q_ws + qbase + 32);

        // S = Q K^T over 14 column tiles, K from swizzled LDS
        f32x4 sacc[14];
        #pragma unroll
        for (int t = 0; t < 14; ++t) sacc[t] = (f32x4){0.f, 0.f, 0.f, 0.f};
        #pragma unroll
        for (int mt = 0; mt < 14; ++mt) {
            const int row = mt * 16 + c16;
            const int sw  = (row & 7) << 3;
            bf16x8 kb0 = *(const bf16x8*)&k_lds[row * 64 + ((g * 8) ^ sw)];
            bf16x8 kb1 = *(const bf16x8*)&k_lds[row * 64 + ((32 + g * 8) ^ sw)];
            sacc[mt] = __builtin_amdgcn_mfma_f32_16x16x32_bf16(qa0, kb0, sacc[mt], 0, 0, 0);
            sacc[mt] = __builtin_amdgcn_mfma_f32_16x16x32_bf16(qa1, kb1, sacc[mt], 0, 0, 0);
        }

        // + rpb, mask m>=197, row max (rows live in 16-lane groups)
        float mx[4] = {-1e30f, -1e30f, -1e30f, -1e30f};
        #pragma unroll
        for (int rg = 0; rg < 4; ++rg) {
            const int n = rt * 16 + g * 4 + rg;
            #pragma unroll
            for (int mt = 0; mt < 14; ++mt) {
                const int m = mt * 16 + c16;
                float s = sacc[mt][rg];
                if (n < NTOK && m < NTOK) s += rpb_full[(size_t)h * NPAIR + n * NTOK + m];
                else                      s = -1e30f;
                sacc[mt][rg] = s;
                mx[rg] = fmaxf(mx[rg], s);
            }
        }
        #pragma unroll
        for (int off = 1; off < 16; off <<= 1)
            #pragma unroll
            for (int rg = 0; rg < 4; ++rg)
                mx[rg] = fmaxf(mx[rg], __shfl_xor(mx[rg], off, 64));

        // P = exp(S - max), row sums, stage P (bf16) to per-wave LDS slab
        float sm[4] = {0.f, 0.f, 0.f, 0.f};
        #pragma unroll
        for (int mt = 0; mt < 14; ++mt)
            #pragma unroll
            for (int rg = 0; rg < 4; ++rg) {
                float p = exp2f((sacc[mt][rg] - mx[rg]) * 1.44269504f);
                sm[rg] += p;
                p_base[(g * 4 + rg) * 232 + mt * 16 + c16] = f2bf(p);
            }
        #pragma unroll
        for (int off = 1; off < 16; off <<= 1)
            #pragma unroll
            for (int rg = 0; rg < 4; ++rg)
                sm[rg] += __shfl_xor(sm[rg], off, 64);
        // per-wave P-write -> P-read ordering (LDS ops are in-order per wave;
        // the waitcnt + memory clobber stops compiler reordering)
        asm volatile("s_waitcnt lgkmcnt(0)" ::: "memory");

        // O = P @ V : A = P from LDS, B = V from global v^T (L1-resident)
        f32x4 oacc[4] = {};
        #pragma unroll
        for (int ks = 0; ks < 7; ++ks) {
            const int kk = ks * 32 + g * 8;
            bf16x8 pa = *(const bf16x8*)&p_base[c16 * 232 + kk];
            #pragma unroll
            for (int j = 0; j < 4; ++j) {
                const int d = j * 16 + c16;
                bf16x8 vbf = *(const bf16x8*)(vt_ws + ((size_t)bh * HD + d) * MPAD + kk);
                oacc[j] = __builtin_amdgcn_mfma_f32_16x16x32_bf16(pa, vbf, oacc[j], 0, 0, 0);
            }
        }

        // normalize + store o_ws[t][h*64+d]
        #pragma unroll
        for (int rg = 0; rg < 4; ++rg) {
            const int n = rt * 16 + g * 4 + rg;
            if (n >= NTOK) continue;
            const float inv = 1.0f / sm[rg];
            #pragma unroll
            for (int j = 0; j < 4; ++j)
                o_ws[((size_t)(b * NTOK + n)) * DIMC + h * HD + j * 16 + c16] =
                    f2bf(oacc[j][rg] * inv);
        }
    }
}

// ---------------------------------------------------------------------------
// Kernel 3: proj GEMM (o_ws bf16 @ pw_bf^T + proj_b) -> fp32 out; 2-phase dbuf
// ---------------------------------------------------------------------------
__global__ __launch_bounds__(256) void proj_gemm_kernel(
    const short* __restrict__ a, const short* __restrict__ wb,
    const float* __restrict__ pb, float* __restrict__ out) {
    __shared__ __align__(16) short lds_a0[128 * 64];
    __shared__ __align__(16) short lds_a1[128 * 64];
    __shared__ __align__(16) short lds_b0[128 * 64];
    __shared__ __align__(16) short lds_b1[128 * 64];
    const int tid  = threadIdx.x;
    const int lane = tid & 63;
    const int wv   = tid >> 6;
    const int wr   = wv >> 1, wc = wv & 1;
    const int bm   = blockIdx.y, bn = blockIdx.x;
    const int g    = lane >> 4, c16 = lane & 15;

    f32x4 acc[4][4] = {};

    const int lrow = lane >> 3;
    const int lcol = (lane & 7) * 8;
    const short* aptr[4];
    const short* bptr[4];
    #pragma unroll
    for (int i = 0; i < 4; ++i) {
        const int r  = (wv * 4 + i) * 8 + lrow;
        int gr = bm * 128 + r; if (gr > M_TOK - 1) gr = M_TOK - 1;
        aptr[i] = a  + (size_t)gr * DIMC + lcol;
        bptr[i] = wb + (size_t)(bn * 128 + r) * DIMC + lcol;
    }

    STAGE(lds_a0, lds_b0, 0);
    __syncthreads();
    #pragma unroll
    for (int kp = 0; kp < 6; ++kp) {
        STAGE(lds_a1, lds_b1, 2 * kp + 1);
        COMPUTE(lds_a0, lds_b0);
        __syncthreads();
        if (kp < 5) { STAGE(lds_a0, lds_b0, 2 * kp + 2); }
        COMPUTE(lds_a1, lds_b1);
        if (kp < 5) __syncthreads();
    }

    #pragma unroll
    for (int i = 0; i < 4; ++i) {
        const int tbase = bm * 128 + wr * 64 + i * 16 + (g << 2);
        #pragma unroll
        for (int j = 0; j < 4; ++j) {
            const int c   = bn * 128 + wc * 64 + j * 16 + c16;
            const float bias = pb[c];
            #pragma unroll
            for (int rg = 0; rg < 4; ++rg) {
                const int tt = tbase + rg;
                if (tt >= M_TOK) continue;
                out[(size_t)tt * DIMC + c] = acc[i][j][rg] + bias;
            }
        }
    }
}

// ---------------------------------------------------------------------------
// Workspace layout (bytes):
//   q_ws   : 19,368,192   @ 0
//   k_ws   : 19,368,192   @ 19,368,192
//   vt_ws  : 22,020,096   @ 38,736,384
//   x_bf / o_ws : 19,365,888 @ 60,756,480  (aliased: x_bf dead before attn)
//   rpb    :  1,862,832   @ 80,122,368
//   w_bf   :  3,538,944   @ 81,985,200
//   pw_bf  :  1,179,648   @ 85,524,144    total 86,703,792
// ---------------------------------------------------------------------------
extern "C" void kernel_launch(void* const* d_in, const int* in_sizes, int n_in,
                              void* d_out, int out_size, void* d_ws, size_t ws_size,
                              hipStream_t stream) {
    const float* x       = (const float*)d_in[0];
    const float* qkv_w   = (const float*)d_in[1];
    const float* q_bias  = (const float*)d_in[2];
    const float* v_bias  = (const float*)d_in[3];
    const float* rpb_tab = (const float*)d_in[4];
    const float* proj_w  = (const float*)d_in[5];
    const float* proj_b  = (const float*)d_in[6];
    const int*   rel_idx = (const int*)d_in[7];
    float* out = (float*)d_out;

    char* ws = (char*)d_ws;
    short* q_ws     = (short*)(ws);
    short* k_ws     = (short*)(ws + 19368192);
    short* vt_ws    = (short*)(ws + 38736384);
    short* x_bf     = (short*)(ws + 60756480);   // aliased with o_ws
    short* o_ws     = (short*)(ws + 60756480);
    float* rpb_full = (float*)(ws + 80122368);
    short* w_bf     = (short*)(ws + 81985200);
    short* pw_bf    = (short*)(ws + 85524144);

    const int ncvt = (NX + NW + NP) / 4;  // 3,010,560 float4 elements
    cvt_kernel<<<(ncvt + 255) / 256, 256, 0, stream>>>(x, x_bf, qkv_w, w_bf, proj_w, pw_bf);
    rpb_kernel<<<(NPAIR + 255) / 256, 256, 0, stream>>>(rpb_tab, rel_idx, rpb_full);

    qkv_gemm_kernel<<<dim3(18, 99), 256, 0, stream>>>(x_bf, w_bf, q_bias, v_bias,
                                                      q_ws, k_ws, vt_ws);
    attn_kernel<<<768, 256, 0, stream>>>(q_ws, k_ws, vt_ws, rpb_full, o_ws);
    proj_gemm_kernel<<<dim3(6, 99), 256, 0, stream>>>(o_ws, pw_bf, proj_b, out);
}

// Round 6
// 291.504 us; speedup vs baseline: 1.2474x; 1.2474x over previous
//
#include <hip/hip_runtime.h>
#include <hip/hip_bf16.h>

// Problem constants
#define HEADS   12
#define HD      64
#define NTOK    197          // N_PATCH + 1
#define BATCH   64
#define M_TOK   (BATCH*NTOK) // 12608
#define DIMC    768
#define NPAIR   (NTOK*NTOK)  // 38809
#define MPAD    224          // key/m dimension padded to 7*32

typedef __attribute__((ext_vector_type(8))) short bf16x8;  // 8 bf16 (4 VGPRs)
typedef __attribute__((ext_vector_type(4))) short s16x4;
typedef __attribute__((ext_vector_type(4))) float f32x4;

// fp32 -> bf16 round-to-nearest-even
static __device__ __forceinline__ short f2bf(float f) {
    unsigned u = __float_as_uint(f);
    unsigned r = (u + 0x7FFFu + ((u >> 16) & 1u)) >> 16;
    return (short)r;
}

// ---------------------------------------------------------------------------
// Kernel 0a: fused fp32 -> bf16 bulk convert of x, qkv_w, proj_w (one launch)
// ---------------------------------------------------------------------------
#define NX (M_TOK * DIMC)        // 9,682,944
#define NW (3 * DIMC * DIMC)     // 1,769,472
#define NP (DIMC * DIMC)         //   589,824
__global__ void cvt_kernel(const float* __restrict__ s0, short* __restrict__ d0,
                           const float* __restrict__ s1, short* __restrict__ d1,
                           const float* __restrict__ s2, short* __restrict__ d2) {
    int i = (blockIdx.x * 256 + threadIdx.x) * 4;
    const float* s; short* d;
    if (i < NX)                { s = s0 + i; d = d0 + i; }
    else if (i < NX + NW)      { s = s1 + (i - NX); d = d1 + (i - NX); }
    else if (i < NX + NW + NP) { s = s2 + (i - NX - NW); d = d2 + (i - NX - NW); }
    else return;
    const float4 v = *(const float4*)s;
    s16x4 b; b[0] = f2bf(v.x); b[1] = f2bf(v.y); b[2] = f2bf(v.z); b[3] = f2bf(v.w);
    *(s16x4*)d = b;
}

// ---------------------------------------------------------------------------
// Kernel 0b: expand rpb_table via rel_pos_index -> rpb_full[h][n*197+m]
// ---------------------------------------------------------------------------
__global__ void rpb_kernel(const float* __restrict__ table,
                           const int* __restrict__ idx,
                           float* __restrict__ rpb_full) {
    int i = blockIdx.x * 256 + threadIdx.x;
    if (i >= NPAIR) return;
    int id = idx[i];
    #pragma unroll
    for (int h = 0; h < HEADS; ++h)
        rpb_full[(size_t)h * NPAIR + i] = table[id * HEADS + h];
}

// ---------------------------------------------------------------------------
// Shared GEMM building blocks: 128x128 tile, BK=64, 4 waves of 64x64,
// 2-phase double-buffered staging.
// ---------------------------------------------------------------------------
#define STAGE(LA, LB, kt)                                                       \
    _Pragma("unroll")                                                           \
    for (int i = 0; i < 4; ++i) {                                               \
        __builtin_amdgcn_global_load_lds(                                       \
            (const __attribute__((address_space(1))) void*)(aptr[i] + (kt) * 64),\
            (__attribute__((address_space(3))) void*)&LA[(wv * 4 + i) * 512],   \
            16, 0, 0);                                                          \
        __builtin_amdgcn_global_load_lds(                                       \
            (const __attribute__((address_space(1))) void*)(bptr[i] + (kt) * 64),\
            (__attribute__((address_space(3))) void*)&LB[(wv * 4 + i) * 512],   \
            16, 0, 0);                                                          \
    }

#define COMPUTE(LA, LB)                                                         \
    _Pragma("unroll")                                                           \
    for (int ks = 0; ks < 2; ++ks) {                                            \
        bf16x8 af[4], bfr[4];                                                   \
        const int kk = ks * 32 + (g << 3);                                      \
        _Pragma("unroll")                                                       \
        for (int i = 0; i < 4; ++i)                                             \
            af[i] = *(const bf16x8*)&LA[(wr * 64 + i * 16 + c16) * 64 + kk];    \
        _Pragma("unroll")                                                       \
        for (int j = 0; j < 4; ++j)                                             \
            bfr[j] = *(const bf16x8*)&LB[(wc * 64 + j * 16 + c16) * 64 + kk];   \
        _Pragma("unroll")                                                       \
        for (int i = 0; i < 4; ++i)                                             \
            _Pragma("unroll")                                                   \
            for (int j = 0; j < 4; ++j)                                         \
                acc[i][j] = __builtin_amdgcn_mfma_f32_16x16x32_bf16(            \
                    af[i], bfr[j], acc[i][j], 0, 0, 0);                         \
    }

// ---------------------------------------------------------------------------
// Kernel 1: QKV GEMM (bf16 in), epilogue scatters q (scaled), k, v^T.
// ---------------------------------------------------------------------------
__global__ __launch_bounds__(256) void qkv_gemm_kernel(
    const short* __restrict__ xb, const short* __restrict__ wb,
    const float* __restrict__ qb, const float* __restrict__ vb,
    short* __restrict__ q_ws, short* __restrict__ k_ws,
    short* __restrict__ vt_ws) {
    __shared__ __align__(16) short lds_a0[128 * 64];
    __shared__ __align__(16) short lds_a1[128 * 64];
    __shared__ __align__(16) short lds_b0[128 * 64];
    __shared__ __align__(16) short lds_b1[128 * 64];
    const int tid  = threadIdx.x;
    const int lane = tid & 63;
    const int wv   = tid >> 6;           // 0..3
    const int wr   = wv >> 1, wc = wv & 1;
    const int bm   = blockIdx.y, bn = blockIdx.x;
    const int g    = lane >> 4, c16 = lane & 15;

    f32x4 acc[4][4] = {};

    const int lrow = lane >> 3;
    const int lcol = (lane & 7) * 8;
    const short* aptr[4];
    const short* bptr[4];
    #pragma unroll
    for (int i = 0; i < 4; ++i) {
        const int r  = (wv * 4 + i) * 8 + lrow;
        int gr = bm * 128 + r; if (gr > M_TOK - 1) gr = M_TOK - 1;
        aptr[i] = xb + (size_t)gr * DIMC + lcol;
        bptr[i] = wb + (size_t)(bn * 128 + r) * DIMC + lcol;
    }

    STAGE(lds_a0, lds_b0, 0);
    __syncthreads();
    #pragma unroll
    for (int kp = 0; kp < 6; ++kp) {
        STAGE(lds_a1, lds_b1, 2 * kp + 1);
        COMPUTE(lds_a0, lds_b0);
        __syncthreads();
        if (kp < 5) { STAGE(lds_a0, lds_b0, 2 * kp + 2); }
        COMPUTE(lds_a1, lds_b1);
        if (kp < 5) __syncthreads();
    }

    // epilogue: C/D layout col = lane&15, row = (lane>>4)*4 + reg  [m89-verified]
    #pragma unroll
    for (int i = 0; i < 4; ++i) {
        const int tbase = bm * 128 + wr * 64 + i * 16 + (g << 2);
        #pragma unroll
        for (int j = 0; j < 4; ++j) {
            const int c     = bn * 128 + wc * 64 + j * 16 + c16;
            const int which = c / DIMC;            // 0=q 1=k 2=v
            const int r     = c - which * DIMC;
            const int h     = r >> 6, d = r & 63;
            #pragma unroll
            for (int rg = 0; rg < 4; ++rg) {
                const int tt = tbase + rg;
                if (tt >= M_TOK) continue;
                const int b = tt / NTOK, n = tt - b * NTOK;
                const size_t bh = (size_t)b * HEADS + h;
                float val = acc[i][j][rg];
                if (which == 0) {
                    val = (val + qb[r]) * 0.125f;                    // q scale hd^-0.5
                    q_ws[(bh * NTOK + n) * HD + d] = f2bf(val);
                } else if (which == 1) {
                    k_ws[(bh * NTOK + n) * HD + d] = f2bf(val);
                } else {
                    val += vb[r];
                    vt_ws[(bh * HD + d) * MPAD + n] = f2bf(val);     // transposed for PV B-frags
                }
            }
        }
    }
}

// ---------------------------------------------------------------------------
// Kernel 2: attention. 1 wave per (b,h, 16-row tile) — high TLP; Q/K/V read
// straight from global. XCD-aware id remap: all 13 row-tile blocks of one
// (b,h) share id mod 8 -> same XCD -> K/V/rpb stay in that XCD's L2.
// grid = 9984 = 8 * 13 * 96.
// ---------------------------------------------------------------------------
__global__ __launch_bounds__(64) void attn_kernel(
    const short* __restrict__ q_ws, const short* __restrict__ k_ws,
    const short* __restrict__ vt_ws, const float* __restrict__ rpb_full,
    short* __restrict__ o_ws) {
    __shared__ __align__(16) short p_lds[16 * 232];   // rows padded to 232
    const int lane = threadIdx.x;
    const int id   = blockIdx.x;
    const int slot = id & 7;                          // XCD (round-robin heuristic)
    const int rest = id >> 3;                         // 0..1247
    const int rt   = rest % 13;                       // row tile 0..12
    const int bh   = (rest / 13) * 8 + slot;          // 0..767 (bijective)
    const int b    = bh / HEADS, h = bh - b * HEADS;
    const int g    = lane >> 4, c16 = lane & 15;

    bf16x8 qa0, qa1;
    {
        const size_t base = ((size_t)bh * NTOK + (rt * 16 + c16)) * HD + g * 8;
        qa0 = *(const bf16x8*)(q_ws + base);
        qa1 = *(const bf16x8*)(q_ws + base + 32);
    }

    f32x4 sacc[14];
    #pragma unroll
    for (int t = 0; t < 14; ++t) sacc[t] = (f32x4){0.f, 0.f, 0.f, 0.f};
    #pragma unroll
    for (int mt = 0; mt < 14; ++mt) {
        const size_t base = ((size_t)bh * NTOK + (mt * 16 + c16)) * HD + g * 8;
        bf16x8 kb0 = *(const bf16x8*)(k_ws + base);
        bf16x8 kb1 = *(const bf16x8*)(k_ws + base + 32);
        sacc[mt] = __builtin_amdgcn_mfma_f32_16x16x32_bf16(qa0, kb0, sacc[mt], 0, 0, 0);
        sacc[mt] = __builtin_amdgcn_mfma_f32_16x16x32_bf16(qa1, kb1, sacc[mt], 0, 0, 0);
    }

    float mx[4] = {-1e30f, -1e30f, -1e30f, -1e30f};
    #pragma unroll
    for (int rg = 0; rg < 4; ++rg) {
        const int n = rt * 16 + g * 4 + rg;
        #pragma unroll
        for (int mt = 0; mt < 14; ++mt) {
            const int m = mt * 16 + c16;
            float s = sacc[mt][rg];
            if (n < NTOK && m < NTOK) s += rpb_full[(size_t)h * NPAIR + n * NTOK + m];
            else                      s = -1e30f;
            sacc[mt][rg] = s;
            mx[rg] = fmaxf(mx[rg], s);
        }
    }
    #pragma unroll
    for (int off = 1; off < 16; off <<= 1)
        #pragma unroll
        for (int rg = 0; rg < 4; ++rg)
            mx[rg] = fmaxf(mx[rg], __shfl_xor(mx[rg], off, 64));

    float sm[4] = {0.f, 0.f, 0.f, 0.f};
    #pragma unroll
    for (int mt = 0; mt < 14; ++mt)
        #pragma unroll
        for (int rg = 0; rg < 4; ++rg) {
            float p = exp2f((sacc[mt][rg] - mx[rg]) * 1.44269504f);
            sm[rg] += p;
            p_lds[(g * 4 + rg) * 232 + mt * 16 + c16] = f2bf(p);
        }
    #pragma unroll
    for (int off = 1; off < 16; off <<= 1)
        #pragma unroll
        for (int rg = 0; rg < 4; ++rg)
            sm[rg] += __shfl_xor(sm[rg], off, 64);
    __syncthreads();

    f32x4 oacc[4] = {};
    #pragma unroll
    for (int ks = 0; ks < 7; ++ks) {
        const int kk = ks * 32 + g * 8;
        bf16x8 pa = *(const bf16x8*)&p_lds[c16 * 232 + kk];
        #pragma unroll
        for (int j = 0; j < 4; ++j) {
            const int d = j * 16 + c16;
            bf16x8 vbf = *(const bf16x8*)(vt_ws + ((size_t)bh * HD + d) * MPAD + kk);
            oacc[j] = __builtin_amdgcn_mfma_f32_16x16x32_bf16(pa, vbf, oacc[j], 0, 0, 0);
        }
    }

    #pragma unroll
    for (int rg = 0; rg < 4; ++rg) {
        const int n = rt * 16 + g * 4 + rg;
        if (n >= NTOK) continue;
        const float inv = 1.0f / sm[rg];
        #pragma unroll
        for (int j = 0; j < 4; ++j)
            o_ws[((size_t)(b * NTOK + n)) * DIMC + h * HD + j * 16 + c16] =
                f2bf(oacc[j][rg] * inv);
    }
}

// ---------------------------------------------------------------------------
// Kernel 3: proj GEMM (o_ws bf16 @ pw_bf^T + proj_b) -> fp32 out; 2-phase dbuf
// ---------------------------------------------------------------------------
__global__ __launch_bounds__(256) void proj_gemm_kernel(
    const short* __restrict__ a, const short* __restrict__ wb,
    const float* __restrict__ pb, float* __restrict__ out) {
    __shared__ __align__(16) short lds_a0[128 * 64];
    __shared__ __align__(16) short lds_a1[128 * 64];
    __shared__ __align__(16) short lds_b0[128 * 64];
    __shared__ __align__(16) short lds_b1[128 * 64];
    const int tid  = threadIdx.x;
    const int lane = tid & 63;
    const int wv   = tid >> 6;
    const int wr   = wv >> 1, wc = wv & 1;
    const int bm   = blockIdx.y, bn = blockIdx.x;
    const int g    = lane >> 4, c16 = lane & 15;

    f32x4 acc[4][4] = {};

    const int lrow = lane >> 3;
    const int lcol = (lane & 7) * 8;
    const short* aptr[4];
    const short* bptr[4];
    #pragma unroll
    for (int i = 0; i < 4; ++i) {
        const int r  = (wv * 4 + i) * 8 + lrow;
        int gr = bm * 128 + r; if (gr > M_TOK - 1) gr = M_TOK - 1;
        aptr[i] = a  + (size_t)gr * DIMC + lcol;
        bptr[i] = wb + (size_t)(bn * 128 + r) * DIMC + lcol;
    }

    STAGE(lds_a0, lds_b0, 0);
    __syncthreads();
    #pragma unroll
    for (int kp = 0; kp < 6; ++kp) {
        STAGE(lds_a1, lds_b1, 2 * kp + 1);
        COMPUTE(lds_a0, lds_b0);
        __syncthreads();
        if (kp < 5) { STAGE(lds_a0, lds_b0, 2 * kp + 2); }
        COMPUTE(lds_a1, lds_b1);
        if (kp < 5) __syncthreads();
    }

    #pragma unroll
    for (int i = 0; i < 4; ++i) {
        const int tbase = bm * 128 + wr * 64 + i * 16 + (g << 2);
        #pragma unroll
        for (int j = 0; j < 4; ++j) {
            const int c   = bn * 128 + wc * 64 + j * 16 + c16;
            const float bias = pb[c];
            #pragma unroll
            for (int rg = 0; rg < 4; ++rg) {
                const int tt = tbase + rg;
                if (tt >= M_TOK) continue;
                out[(size_t)tt * DIMC + c] = acc[i][j][rg] + bias;
            }
        }
    }
}

// ---------------------------------------------------------------------------
// Workspace layout (bytes):
//   q_ws   : 19,368,192   @ 0
//   k_ws   : 19,368,192   @ 19,368,192
//   vt_ws  : 22,020,096   @ 38,736,384
//   x_bf / o_ws : 19,365,888 @ 60,756,480  (aliased: x_bf dead before attn)
//   rpb    :  1,862,832   @ 80,122,368
//   w_bf   :  3,538,944   @ 81,985,200
//   pw_bf  :  1,179,648   @ 85,524,144    total 86,703,792
// ---------------------------------------------------------------------------
extern "C" void kernel_launch(void* const* d_in, const int* in_sizes, int n_in,
                              void* d_out, int out_size, void* d_ws, size_t ws_size,
                              hipStream_t stream) {
    const float* x       = (const float*)d_in[0];
    const float* qkv_w   = (const float*)d_in[1];
    const float* q_bias  = (const float*)d_in[2];
    const float* v_bias  = (const float*)d_in[3];
    const float* rpb_tab = (const float*)d_in[4];
    const float* proj_w  = (const float*)d_in[5];
    const float* proj_b  = (const float*)d_in[6];
    const int*   rel_idx = (const int*)d_in[7];
    float* out = (float*)d_out;

    char* ws = (char*)d_ws;
    short* q_ws     = (short*)(ws);
    short* k_ws     = (short*)(ws + 19368192);
    short* vt_ws    = (short*)(ws + 38736384);
    short* x_bf     = (short*)(ws + 60756480);   // aliased with o_ws
    short* o_ws     = (short*)(ws + 60756480);
    float* rpb_full = (float*)(ws + 80122368);
    short* w_bf     = (short*)(ws + 81985200);
    short* pw_bf    = (short*)(ws + 85524144);

    const int ncvt = (NX + NW + NP) / 4;  // 3,010,560 float4 elements
    cvt_kernel<<<(ncvt + 255) / 256, 256, 0, stream>>>(x, x_bf, qkv_w, w_bf, proj_w, pw_bf);
    rpb_kernel<<<(NPAIR + 255) / 256, 256, 0, stream>>>(rpb_tab, rel_idx, rpb_full);

    qkv_gemm_kernel<<<dim3(18, 99), 256, 0, stream>>>(x_bf, w_bf, q_bias, v_bias,
                                                      q_ws, k_ws, vt_ws);
    attn_kernel<<<9984, 64, 0, stream>>>(q_ws, k_ws, vt_ws, rpb_full, o_ws);
    proj_gemm_kernel<<<dim3(6, 99), 256, 0, stream>>>(o_ws, pw_bf, proj_b, out);
}

// Round 7
// 276.202 us; speedup vs baseline: 1.3165x; 1.0554x over previous
//
#include <hip/hip_runtime.h>
#include <hip/hip_bf16.h>

// Problem constants
#define HEADS   12
#define HD      64
#define NTOK    197          // N_PATCH + 1
#define BATCH   64
#define M_TOK   (BATCH*NTOK) // 12608
#define DIMC    768
#define NPAIR   (NTOK*NTOK)  // 38809
#define MPAD    224          // key/m dimension padded to 7*32

typedef __attribute__((ext_vector_type(8))) short bf16x8;  // 8 bf16 (4 VGPRs)
typedef __attribute__((ext_vector_type(4))) short s16x4;
typedef __attribute__((ext_vector_type(4))) float f32x4;

// fp32 -> bf16 round-to-nearest-even
static __device__ __forceinline__ short f2bf(float f) {
    unsigned u = __float_as_uint(f);
    unsigned r = (u + 0x7FFFu + ((u >> 16) & 1u)) >> 16;
    return (short)r;
}

// ---------------------------------------------------------------------------
// Kernel 0a: fused fp32 -> bf16 bulk convert of x, qkv_w, proj_w (one launch)
// ---------------------------------------------------------------------------
#define NX (M_TOK * DIMC)        // 9,682,944
#define NW (3 * DIMC * DIMC)     // 1,769,472
#define NP (DIMC * DIMC)         //   589,824
__global__ void cvt_kernel(const float* __restrict__ s0, short* __restrict__ d0,
                           const float* __restrict__ s1, short* __restrict__ d1,
                           const float* __restrict__ s2, short* __restrict__ d2) {
    int i = (blockIdx.x * 256 + threadIdx.x) * 4;
    const float* s; short* d;
    if (i < NX)                { s = s0 + i; d = d0 + i; }
    else if (i < NX + NW)      { s = s1 + (i - NX); d = d1 + (i - NX); }
    else if (i < NX + NW + NP) { s = s2 + (i - NX - NW); d = d2 + (i - NX - NW); }
    else return;
    const float4 v = *(const float4*)s;
    s16x4 b; b[0] = f2bf(v.x); b[1] = f2bf(v.y); b[2] = f2bf(v.z); b[3] = f2bf(v.w);
    *(s16x4*)d = b;
}

// ---------------------------------------------------------------------------
// Kernel 0b: expand rpb_table via rel_pos_index -> rpb_full[h][n*197+m]
// ---------------------------------------------------------------------------
__global__ void rpb_kernel(const float* __restrict__ table,
                           const int* __restrict__ idx,
                           float* __restrict__ rpb_full) {
    int i = blockIdx.x * 256 + threadIdx.x;
    if (i >= NPAIR) return;
    int id = idx[i];
    #pragma unroll
    for (int h = 0; h < HEADS; ++h)
        rpb_full[(size_t)h * NPAIR + i] = table[id * HEADS + h];
}

// ---------------------------------------------------------------------------
// Shared GEMM building blocks: 128x128 tile, BK=64, 4 waves of 64x64,
// 2-phase double-buffered staging.
// Bank-conflict fix (rule #21, both-sides-or-neither): LDS dest stays LINEAR
// (global_load_lds requirement); the global SOURCE chunk is pre-permuted per
// lane (chunk = (l&7) ^ (l>>3)), so LDS[row][pc] = global[row][pc ^ (row&7)];
// ds_read applies the same XOR -> involution recovers the data, and a 16-lane
// column read now touches 8 distinct 16B slots (2-way = free) instead of 16.
// ---------------------------------------------------------------------------
#define STAGE(LA, LB, kt)                                                       \
    _Pragma("unroll")                                                           \
    for (int i = 0; i < 4; ++i) {                                               \
        __builtin_amdgcn_global_load_lds(                                       \
            (const __attribute__((address_space(1))) void*)(aptr[i] + (kt) * 64),\
            (__attribute__((address_space(3))) void*)&LA[(wv * 4 + i) * 512],   \
            16, 0, 0);                                                          \
        __builtin_amdgcn_global_load_lds(                                       \
            (const __attribute__((address_space(1))) void*)(bptr[i] + (kt) * 64),\
            (__attribute__((address_space(3))) void*)&LB[(wv * 4 + i) * 512],   \
            16, 0, 0);                                                          \
    }

#define COMPUTE(LA, LB)                                                         \
    _Pragma("unroll")                                                           \
    for (int ks = 0; ks < 2; ++ks) {                                            \
        bf16x8 af[4], bfr[4];                                                   \
        const int kk = (((ks * 4 + g) ^ (c16 & 7)) << 3);   /* swizzled read */ \
        _Pragma("unroll")                                                       \
        for (int i = 0; i < 4; ++i)                                             \
            af[i] = *(const bf16x8*)&LA[(wr * 64 + i * 16 + c16) * 64 + kk];    \
        _Pragma("unroll")                                                       \
        for (int j = 0; j < 4; ++j)                                             \
            bfr[j] = *(const bf16x8*)&LB[(wc * 64 + j * 16 + c16) * 64 + kk];   \
        _Pragma("unroll")                                                       \
        for (int i = 0; i < 4; ++i)                                             \
            _Pragma("unroll")                                                   \
            for (int j = 0; j < 4; ++j)                                         \
                acc[i][j] = __builtin_amdgcn_mfma_f32_16x16x32_bf16(            \
                    af[i], bfr[j], acc[i][j], 0, 0, 0);                         \
    }

// ---------------------------------------------------------------------------
// Kernel 1: QKV GEMM (bf16 in), epilogue scatters q (scaled), k, v^T.
// Grid: 1782 flat blocks, m204 bijective XCD swizzle (q=222, r=6) so the 18
// same-bm blocks (sharing an A-panel) land on one XCD's L2.
// ---------------------------------------------------------------------------
__global__ __launch_bounds__(256) void qkv_gemm_kernel(
    const short* __restrict__ xb, const short* __restrict__ wb,
    const float* __restrict__ qb, const float* __restrict__ vb,
    short* __restrict__ q_ws, short* __restrict__ k_ws,
    short* __restrict__ vt_ws) {
    __shared__ __align__(16) short lds_a0[128 * 64];
    __shared__ __align__(16) short lds_a1[128 * 64];
    __shared__ __align__(16) short lds_b0[128 * 64];
    __shared__ __align__(16) short lds_b1[128 * 64];
    const int tid  = threadIdx.x;
    const int lane = tid & 63;
    const int wv   = tid >> 6;           // 0..3
    const int wr   = wv >> 1, wc = wv & 1;
    // XCD-bijective decode: nwg=1782, q=222, r=6
    const int flat = blockIdx.x;
    const int xcd  = flat & 7, pos = flat >> 3;
    const int swz  = ((xcd < 6) ? xcd * 223 : 1338 + (xcd - 6) * 222) + pos;
    const int bm   = swz / 18, bn = swz - bm * 18;
    const int g    = lane >> 4, c16 = lane & 15;

    f32x4 acc[4][4] = {};

    const int lrow = lane >> 3;
    const int lcol = ((lane & 7) ^ lrow) * 8;     // inverse-swizzled source col
    const short* aptr[4];
    const short* bptr[4];
    #pragma unroll
    for (int i = 0; i < 4; ++i) {
        const int r  = (wv * 4 + i) * 8 + lrow;
        int gr = bm * 128 + r; if (gr > M_TOK - 1) gr = M_TOK - 1;
        aptr[i] = xb + (size_t)gr * DIMC + lcol;
        bptr[i] = wb + (size_t)(bn * 128 + r) * DIMC + lcol;
    }

    STAGE(lds_a0, lds_b0, 0);
    __syncthreads();
    #pragma unroll
    for (int kp = 0; kp < 6; ++kp) {
        STAGE(lds_a1, lds_b1, 2 * kp + 1);
        COMPUTE(lds_a0, lds_b0);
        __syncthreads();
        if (kp < 5) { STAGE(lds_a0, lds_b0, 2 * kp + 2); }
        COMPUTE(lds_a1, lds_b1);
        if (kp < 5) __syncthreads();
    }

    // epilogue: C/D layout col = lane&15, row = (lane>>4)*4 + reg  [m89-verified]
    #pragma unroll
    for (int i = 0; i < 4; ++i) {
        const int tbase = bm * 128 + wr * 64 + i * 16 + (g << 2);
        #pragma unroll
        for (int j = 0; j < 4; ++j) {
            const int c     = bn * 128 + wc * 64 + j * 16 + c16;
            const int which = c / DIMC;            // 0=q 1=k 2=v
            const int r     = c - which * DIMC;
            const int h     = r >> 6, d = r & 63;
            #pragma unroll
            for (int rg = 0; rg < 4; ++rg) {
                const int tt = tbase + rg;
                if (tt >= M_TOK) continue;
                const int b = tt / NTOK, n = tt - b * NTOK;
                const size_t bh = (size_t)b * HEADS + h;
                float val = acc[i][j][rg];
                if (which == 0) {
                    val = (val + qb[r]) * 0.125f;                    // q scale hd^-0.5
                    q_ws[(bh * NTOK + n) * HD + d] = f2bf(val);
                } else if (which == 1) {
                    k_ws[(bh * NTOK + n) * HD + d] = f2bf(val);
                } else {
                    val += vb[r];
                    vt_ws[(bh * HD + d) * MPAD + n] = f2bf(val);     // transposed for PV B-frags
                }
            }
        }
    }
}

// ---------------------------------------------------------------------------
// Kernel 2: attention. 1 wave per (b,h, 16-row tile) — high TLP; Q/K/V read
// straight from global. XCD-aware id remap: all 13 row-tile blocks of one
// (b,h) share id mod 8 -> same XCD -> K/V/rpb stay in that XCD's L2.
// grid = 9984 = 8 * 13 * 96.
// ---------------------------------------------------------------------------
__global__ __launch_bounds__(64) void attn_kernel(
    const short* __restrict__ q_ws, const short* __restrict__ k_ws,
    const short* __restrict__ vt_ws, const float* __restrict__ rpb_full,
    short* __restrict__ o_ws) {
    __shared__ __align__(16) short p_lds[16 * 232];   // rows padded to 232
    const int lane = threadIdx.x;
    const int id   = blockIdx.x;
    const int slot = id & 7;                          // XCD (round-robin heuristic)
    const int rest = id >> 3;                         // 0..1247
    const int rt   = rest % 13;                       // row tile 0..12
    const int bh   = (rest / 13) * 8 + slot;          // 0..767 (bijective)
    const int b    = bh / HEADS, h = bh - b * HEADS;
    const int g    = lane >> 4, c16 = lane & 15;

    bf16x8 qa0, qa1;
    {
        const size_t base = ((size_t)bh * NTOK + (rt * 16 + c16)) * HD + g * 8;
        qa0 = *(const bf16x8*)(q_ws + base);
        qa1 = *(const bf16x8*)(q_ws + base + 32);
    }

    f32x4 sacc[14];
    #pragma unroll
    for (int t = 0; t < 14; ++t) sacc[t] = (f32x4){0.f, 0.f, 0.f, 0.f};
    #pragma unroll
    for (int mt = 0; mt < 14; ++mt) {
        const size_t base = ((size_t)bh * NTOK + (mt * 16 + c16)) * HD + g * 8;
        bf16x8 kb0 = *(const bf16x8*)(k_ws + base);
        bf16x8 kb1 = *(const bf16x8*)(k_ws + base + 32);
        sacc[mt] = __builtin_amdgcn_mfma_f32_16x16x32_bf16(qa0, kb0, sacc[mt], 0, 0, 0);
        sacc[mt] = __builtin_amdgcn_mfma_f32_16x16x32_bf16(qa1, kb1, sacc[mt], 0, 0, 0);
    }

    float mx[4] = {-1e30f, -1e30f, -1e30f, -1e30f};
    #pragma unroll
    for (int rg = 0; rg < 4; ++rg) {
        const int n = rt * 16 + g * 4 + rg;
        #pragma unroll
        for (int mt = 0; mt < 14; ++mt) {
            const int m = mt * 16 + c16;
            float s = sacc[mt][rg];
            if (n < NTOK && m < NTOK) s += rpb_full[(size_t)h * NPAIR + n * NTOK + m];
            else                      s = -1e30f;
            sacc[mt][rg] = s;
            mx[rg] = fmaxf(mx[rg], s);
        }
    }
    #pragma unroll
    for (int off = 1; off < 16; off <<= 1)
        #pragma unroll
        for (int rg = 0; rg < 4; ++rg)
            mx[rg] = fmaxf(mx[rg], __shfl_xor(mx[rg], off, 64));

    float sm[4] = {0.f, 0.f, 0.f, 0.f};
    #pragma unroll
    for (int mt = 0; mt < 14; ++mt)
        #pragma unroll
        for (int rg = 0; rg < 4; ++rg) {
            float p = exp2f((sacc[mt][rg] - mx[rg]) * 1.44269504f);
            sm[rg] += p;
            p_lds[(g * 4 + rg) * 232 + mt * 16 + c16] = f2bf(p);
        }
    #pragma unroll
    for (int off = 1; off < 16; off <<= 1)
        #pragma unroll
        for (int rg = 0; rg < 4; ++rg)
            sm[rg] += __shfl_xor(sm[rg], off, 64);
    __syncthreads();

    f32x4 oacc[4] = {};
    #pragma unroll
    for (int ks = 0; ks < 7; ++ks) {
        const int kk = ks * 32 + g * 8;
        bf16x8 pa = *(const bf16x8*)&p_lds[c16 * 232 + kk];
        #pragma unroll
        for (int j = 0; j < 4; ++j) {
            const int d = j * 16 + c16;
            bf16x8 vbf = *(const bf16x8*)(vt_ws + ((size_t)bh * HD + d) * MPAD + kk);
            oacc[j] = __builtin_amdgcn_mfma_f32_16x16x32_bf16(pa, vbf, oacc[j], 0, 0, 0);
        }
    }

    #pragma unroll
    for (int rg = 0; rg < 4; ++rg) {
        const int n = rt * 16 + g * 4 + rg;
        if (n >= NTOK) continue;
        const float inv = 1.0f / sm[rg];
        #pragma unroll
        for (int j = 0; j < 4; ++j)
            o_ws[((size_t)(b * NTOK + n)) * DIMC + h * HD + j * 16 + c16] =
                f2bf(oacc[j][rg] * inv);
    }
}

// ---------------------------------------------------------------------------
// Kernel 3: proj GEMM (o_ws bf16 @ pw_bf^T + proj_b) -> fp32 out; 2-phase dbuf
// Grid: 594 flat blocks, XCD swizzle (q=74, r=2).
// ---------------------------------------------------------------------------
__global__ __launch_bounds__(256) void proj_gemm_kernel(
    const short* __restrict__ a, const short* __restrict__ wb,
    const float* __restrict__ pb, float* __restrict__ out) {
    __shared__ __align__(16) short lds_a0[128 * 64];
    __shared__ __align__(16) short lds_a1[128 * 64];
    __shared__ __align__(16) short lds_b0[128 * 64];
    __shared__ __align__(16) short lds_b1[128 * 64];
    const int tid  = threadIdx.x;
    const int lane = tid & 63;
    const int wv   = tid >> 6;
    const int wr   = wv >> 1, wc = wv & 1;
    // XCD-bijective decode: nwg=594, q=74, r=2
    const int flat = blockIdx.x;
    const int xcd  = flat & 7, pos = flat >> 3;
    const int swz  = ((xcd < 2) ? xcd * 75 : 150 + (xcd - 2) * 74) + pos;
    const int bm   = swz / 6, bn = swz - bm * 6;
    const int g    = lane >> 4, c16 = lane & 15;

    f32x4 acc[4][4] = {};

    const int lrow = lane >> 3;
    const int lcol = ((lane & 7) ^ lrow) * 8;     // inverse-swizzled source col
    const short* aptr[4];
    const short* bptr[4];
    #pragma unroll
    for (int i = 0; i < 4; ++i) {
        const int r  = (wv * 4 + i) * 8 + lrow;
        int gr = bm * 128 + r; if (gr > M_TOK - 1) gr = M_TOK - 1;
        aptr[i] = a  + (size_t)gr * DIMC + lcol;
        bptr[i] = wb + (size_t)(bn * 128 + r) * DIMC + lcol;
    }

    STAGE(lds_a0, lds_b0, 0);
    __syncthreads();
    #pragma unroll
    for (int kp = 0; kp < 6; ++kp) {
        STAGE(lds_a1, lds_b1, 2 * kp + 1);
        COMPUTE(lds_a0, lds_b0);
        __syncthreads();
        if (kp < 5) { STAGE(lds_a0, lds_b0, 2 * kp + 2); }
        COMPUTE(lds_a1, lds_b1);
        if (kp < 5) __syncthreads();
    }

    #pragma unroll
    for (int i = 0; i < 4; ++i) {
        const int tbase = bm * 128 + wr * 64 + i * 16 + (g << 2);
        #pragma unroll
        for (int j = 0; j < 4; ++j) {
            const int c   = bn * 128 + wc * 64 + j * 16 + c16;
            const float bias = pb[c];
            #pragma unroll
            for (int rg = 0; rg < 4; ++rg) {
                const int tt = tbase + rg;
                if (tt >= M_TOK) continue;
                out[(size_t)tt * DIMC + c] = acc[i][j][rg] + bias;
            }
        }
    }
}

// ---------------------------------------------------------------------------
// Workspace layout (bytes):
//   q_ws   : 19,368,192   @ 0
//   k_ws   : 19,368,192   @ 19,368,192
//   vt_ws  : 22,020,096   @ 38,736,384
//   x_bf / o_ws : 19,365,888 @ 60,756,480  (aliased: x_bf dead before attn)
//   rpb    :  1,862,832   @ 80,122,368
//   w_bf   :  3,538,944   @ 81,985,200
//   pw_bf  :  1,179,648   @ 85,524,144    total 86,703,792
// ---------------------------------------------------------------------------
extern "C" void kernel_launch(void* const* d_in, const int* in_sizes, int n_in,
                              void* d_out, int out_size, void* d_ws, size_t ws_size,
                              hipStream_t stream) {
    const float* x       = (const float*)d_in[0];
    const float* qkv_w   = (const float*)d_in[1];
    const float* q_bias  = (const float*)d_in[2];
    const float* v_bias  = (const float*)d_in[3];
    const float* rpb_tab = (const float*)d_in[4];
    const float* proj_w  = (const float*)d_in[5];
    const float* proj_b  = (const float*)d_in[6];
    const int*   rel_idx = (const int*)d_in[7];
    float* out = (float*)d_out;

    char* ws = (char*)d_ws;
    short* q_ws     = (short*)(ws);
    short* k_ws     = (short*)(ws + 19368192);
    short* vt_ws    = (short*)(ws + 38736384);
    short* x_bf     = (short*)(ws + 60756480);   // aliased with o_ws
    short* o_ws     = (short*)(ws + 60756480);
    float* rpb_full = (float*)(ws + 80122368);
    short* w_bf     = (short*)(ws + 81985200);
    short* pw_bf    = (short*)(ws + 85524144);

    const int ncvt = (NX + NW + NP) / 4;  // 3,010,560 float4 elements
    cvt_kernel<<<(ncvt + 255) / 256, 256, 0, stream>>>(x, x_bf, qkv_w, w_bf, proj_w, pw_bf);
    rpb_kernel<<<(NPAIR + 255) / 256, 256, 0, stream>>>(rpb_tab, rel_idx, rpb_full);

    qkv_gemm_kernel<<<1782, 256, 0, stream>>>(x_bf, w_bf, q_bias, v_bias,
                                              q_ws, k_ws, vt_ws);
    attn_kernel<<<9984, 64, 0, stream>>>(q_ws, k_ws, vt_ws, rpb_full, o_ws);
    proj_gemm_kernel<<<594, 256, 0, stream>>>(o_ws, pw_bf, proj_b, out);
}